// Round 8
// baseline (302.567 us; speedup 1.0000x reference)
//
#include <hip/hip_runtime.h>

// CRF forward: B=512, T=1024, N=64. fwd/bwd split, one wave per chain.
// Round 18: R17 (P=2 half-split) + SINGLE-WAIT DISCIPLINE.
// Calibration through R17: per-step = ~128 cyc VALU issue (matches
// VALUBusy 17.9% x 712cyc) + ~586 cyc non-VALU stall. 9 DS ops can't
// explain 586 by per-instruction constants (~250-300 max). Hypothesis:
// the compiler's STAGED lgkm waits (wait(6)..wait(4)..wait(0) to start
// FMAs early) cost a full wave-stall + resume EACH at 1 wave/SIMD;
// ~5-6 events x ~50cyc resume + latency ~= 550. Fix: force ONE wait
// event per step: [write + 8 reads] -> sched_barrier(0) ->
// asm s_waitcnt lgkmcnt(0) -> sched_barrier(0) -> [all FMAs].
// Everything else byte-identical to R17 (math verified absmax 0.0 in
// rounds 10/12-17).
//   fwd: a' = (E^T a) * w ; bwd: a' = E (w a); exponent-only rescale
//   every 4 steps; out = ln2 * (off_f + off_b + log2(sum_i a_i b_i)).

typedef float f2 __attribute__((ext_vector_type(2)));
typedef float f4 __attribute__((ext_vector_type(4)));

constexpr int Tt = 1024;
constexpr int Nn = 64;
constexpr int ES  = 68;  // Erow stride (floats)
constexpr int EPS = 68;  // Eperm per-thread stride (floats), 272B
constexpr float LN2 = 0.69314718055994530942f;

// Pair-sum across the 32-lane halves (bit 5), order-robust: swap with a
// copy, add both outputs. s_nop 1 guards the VALU-write -> cross-lane-read
// hazard.
__device__ __forceinline__ float xsum32(float x) {
    float a = x, b = x;
    asm("s_nop 1\n\tv_permlane32_swap_b32 %0, %1" : "+v"(a), "+v"(b));
    return a + b;
}

__global__ __launch_bounds__(128, 1) void crf_fwd(
    const float* __restrict__ unary,
    const int*   __restrict__ lengths,
    const float* __restrict__ trans,
    float*       __restrict__ out)
{
    const int b    = blockIdx.x;
    const int tid  = threadIdx.x;
    const int w    = tid >> 6;   // 0 = forward wave, 1 = backward wave
    const int lane = tid & 63;
    const int q    = lane & 31;  // output index low bits
    const int h    = lane >> 5;  // input half

    __shared__ float Erow[Nn * ES];     // Erow[i*ES+j] = exp(trans[i][j])
    __shared__ float Eperm[128 * EPS];  // per-thread E in gather order
    __shared__ __align__(16) float shp[2][Nn];  // per-wave alpha broadcast
    __shared__ float shb[Nn];           // beta at midpoint (combine)
    __shared__ int   sh_off_b;          // bwd exponent offset

    // Phase 1: stage E = exp(trans) row-major (coalesced global reads).
    #pragma unroll
    for (int c = 0; c < (Nn * Nn) / 128; ++c) {
        int idx = c * 128 + tid;
        Erow[(idx >> 6) * ES + (idx & 63)] = __expf(trans[idx]);
    }
    __syncthreads();

    // Phase 2: this thread's 64 E values in half-slice order:
    //   v<32:  o = q,     i = 32h + v        (slot A)
    //   v>=32: o = q+32,  i = 32h + (v-32)   (slot B)
    //   fwd: M[o][i] = E[i][o]  (a' = E^T a);  bwd: M[o][i] = E[o][i].
    float* ep = &Eperm[tid * EPS];
    #pragma unroll
    for (int v = 0; v < 64; ++v) {
        int o = q + 32 * (v >> 5);
        int i = 32 * h + (v & 31);
        ep[v] = (w == 0) ? Erow[i * ES + o] : Erow[o * ES + i];
    }
    // Same-thread DS write->read is in-order; no barrier needed.

    // Phase 3: contiguous f4 loads into NAMED registers (residency pattern
    // proven in rounds 10/11/14-17), then pin.
    const f4* eb = (const f4*)ep;
    f4 EA0  = eb[0],  EA1  = eb[1],  EA2  = eb[2],  EA3  = eb[3];
    f4 EA4  = eb[4],  EA5  = eb[5],  EA6  = eb[6],  EA7  = eb[7];
    f4 EA8  = eb[8],  EA9  = eb[9],  EA10 = eb[10], EA11 = eb[11];
    f4 EA12 = eb[12], EA13 = eb[13], EA14 = eb[14], EA15 = eb[15];
    asm volatile("" : "+v"(EA0),  "+v"(EA1),  "+v"(EA2),  "+v"(EA3),
                      "+v"(EA4),  "+v"(EA5),  "+v"(EA6),  "+v"(EA7),
                      "+v"(EA8),  "+v"(EA9),  "+v"(EA10), "+v"(EA11),
                      "+v"(EA12), "+v"(EA13), "+v"(EA14), "+v"(EA15));

    int L = lengths[b];
    L = L < 1 ? 1 : (L > Tt ? Tt : L);
    const int m2 = (L - 1) >> 1;

    const float* ub = unary + (size_t)b * Tt * Nn;

    const int trips = (w == 0) ? m2 : (L - 1 - m2);
    const int tbase = (w == 0) ? 1 : (L - 1);
    const int dir   = (w == 0) ? 1 : -1;

    // Exp-domain state + exponent offset.
    float acc = (w == 0) ? __expf(ub[lane]) : 1.0f;
    int   off = 0;

    float* myp = shp[w];
    const f4* rowp = (const f4*)&shp[w][32 * h];  // half-uniform address

    // 8-step lookahead: wq* = exp'd w for steps s0..s0+3,
    //                   uq* = raw u for steps s0+4..s0+7.
    const int smax = trips > 0 ? trips - 1 : 0;
    float wq0, wq1, wq2, wq3, uq0, uq1, uq2, uq3;
    {
        int c0 = 0 < smax ? 0 : smax, c1 = 1 < smax ? 1 : smax;
        int c2 = 2 < smax ? 2 : smax, c3 = 3 < smax ? 3 : smax;
        wq0 = __expf(ub[(tbase + dir * c0) * Nn + lane]);
        wq1 = __expf(ub[(tbase + dir * c1) * Nn + lane]);
        wq2 = __expf(ub[(tbase + dir * c2) * Nn + lane]);
        wq3 = __expf(ub[(tbase + dir * c3) * Nn + lane]);
        int c4 = 4 < smax ? 4 : smax, c5 = 5 < smax ? 5 : smax;
        int c6 = 6 < smax ? 6 : smax, c7 = 7 < smax ? 7 : smax;
        uq0 = ub[(tbase + dir * c4) * Nn + lane];
        uq1 = ub[(tbase + dir * c5) * Nn + lane];
        uq2 = ub[(tbase + dir * c6) * Nn + lane];
        uq3 = ub[(tbase + dir * c7) * Nn + lane];
    }

    for (int s0 = 0; s0 < trips; s0 += 4) {
        // Issue raw loads 8 ahead; exp the 4-ahead batch. Both off-chain.
        float un0, un1, un2, un3, wn0, wn1, wn2, wn3;
        {
            int c0 = s0 + 8,  c1 = s0 + 9,  c2 = s0 + 10, c3 = s0 + 11;
            c0 = c0 > smax ? smax : c0;  c1 = c1 > smax ? smax : c1;
            c2 = c2 > smax ? smax : c2;  c3 = c3 > smax ? smax : c3;
            un0 = ub[(tbase + dir * c0) * Nn + lane];
            un1 = ub[(tbase + dir * c1) * Nn + lane];
            un2 = ub[(tbase + dir * c2) * Nn + lane];
            un3 = ub[(tbase + dir * c3) * Nn + lane];
        }
        wn0 = __expf(uq0); wn1 = __expf(uq1);
        wn2 = __expf(uq2); wn3 = __expf(uq3);

        #pragma unroll
        for (int k = 0; k < 4; ++k) {
            if (s0 + k >= trips) break;  // wave-uniform

            float wk = (k == 0) ? wq0 : (k == 1) ? wq1 : (k == 2) ? wq2 : wq3;

            // fwd: a' = (E^T a) * w   (w on output)
            // bwd: a' = E (w * a)     (w on input)
            float src = (w != 0) ? acc * wk : acc;

            // Publish alpha; read own input half (8x b128). SINGLE-WAIT
            // DISCIPLINE: issue all 9 DS ops, fence, ONE s_waitcnt, fence,
            // then all consumers. (Rule #18: SB(0) after the asm wait so
            // VALU consumers can't hoist past it.)
            myp[lane] = src;
            f4 av0 = rowp[0], av1 = rowp[1], av2 = rowp[2], av3 = rowp[3];
            f4 av4 = rowp[4], av5 = rowp[5], av6 = rowp[6], av7 = rowp[7];
            __builtin_amdgcn_sched_barrier(0);
            asm volatile("s_waitcnt lgkmcnt(0)" ::: "memory");
            __builtin_amdgcn_sched_barrier(0);

            // Partials: Pa = <half, M[q][half]>, Pb = <half, M[q+32][half]>.
            // Two interleaved chains each for ILP.
            f4 Aa = av0 * EA0;       f4 Ab = av1 * EA1;
            Aa = av2 * EA2 + Aa;     Ab = av3 * EA3 + Ab;
            Aa = av4 * EA4 + Aa;     Ab = av5 * EA5 + Ab;
            Aa = av6 * EA6 + Aa;     Ab = av7 * EA7 + Ab;
            f4 Ba = av0 * EA8;       f4 Bb = av1 * EA9;
            Ba = av2 * EA10 + Ba;    Bb = av3 * EA11 + Bb;
            Ba = av4 * EA12 + Ba;    Bb = av5 * EA13 + Bb;
            Ba = av6 * EA14 + Ba;    Bb = av7 * EA15 + Bb;

            f4 At = Aa + Ab;         f4 Bt = Ba + Bb;
            f2 Ah = At.xy + At.zw;   f2 Bh = Bt.xy + Bt.zw;
            float Pa = Ah[0] + Ah[1];
            float Pb = Bh[0] + Bh[1];

            // Cross-half reduce: one permlane32 pair-sum per output.
            float za = xsum32(Pa);   // out[q],    replicated both halves
            float zb = xsum32(Pb);   // out[q+32], replicated both halves
            float z  = (lane & 32) ? zb : za;

            acc = (w == 0) ? z * wk : z;
        }

        // Exact exponent-only rescale (once per 4 steps; keeps fp32 in
        // range: worst drift 4 steps * ~14 bits + ~10 bits lane spread).
        {
            unsigned s0b = (unsigned)__builtin_amdgcn_readfirstlane(
                (int)__float_as_uint(acc));
            int e = (int)((s0b >> 23) & 0xFF) - 127;
            off += e;
            acc *= __uint_as_float((unsigned)(127 - e) << 23);
        }

        wq0 = wn0; wq1 = wn1; wq2 = wn2; wq3 = wn3;
        uq0 = un0; uq1 = un1; uq2 = un2; uq3 = un3;
    }

    // Combine: out[b] = ln2 * (off_f + off_b + log2(sum_i a_i * b_i)).
    if (w == 1) {
        shb[lane] = acc;
        if (lane == 0) sh_off_b = off;
    }
    __syncthreads();
    if (w == 0) {
        float v = acc * shb[lane];
        float ssum = v;
        #pragma unroll
        for (int k = 32; k >= 1; k >>= 1)
            ssum += __shfl_xor(ssum, k, 64);
        if (lane == 0) {
            float l2 = __builtin_amdgcn_logf(ssum);  // v_log_f32 = log2
            out[b] = LN2 * ((float)(off + sh_off_b) + l2);
        }
    }
}

extern "C" void kernel_launch(void* const* d_in, const int* in_sizes, int n_in,
                              void* d_out, int out_size, void* d_ws, size_t ws_size,
                              hipStream_t stream) {
    const float* unary   = (const float*)d_in[0];
    const int*   lengths = (const int*)d_in[1];
    const float* trans   = (const float*)d_in[2];
    float*       out     = (float*)d_out;

    const int Bb = in_sizes[1];  // 512
    crf_fwd<<<Bb, 128, 0, stream>>>(unary, lengths, trans, out);
}

// Round 9
// 287.925 us; speedup vs baseline: 1.0509x; 1.0509x over previous
//
#include <hip/hip_runtime.h>

// CRF forward: B=512, T=1024, N=64. Exp-domain recurrence, fwd/bwd split.
// Round 19: LENGTH-SORTED PAIRING + 1 block/CU. The R17 step body is kept
// VERBATIM (best measured: 152us; R18's single-wait fence was -4%, dropped).
// Remaining unexplained cost is structure-insensitive; the one thing never
// varied is work placement: 512 blocks land 2/CU with RANDOM length pairing
// -> worst CU gets ~1700-1900 steps-worth of chain work. Fix: kernel 1
// ranks chains by length (one 512-thread block, O(B^2) count-rank, ~us);
// kernel 2 runs grid=B/2, block=256 (4 waves): block i = chains sorted[i]
// (long) + sorted[B-1-i] (short), fwd+bwd waves each -> every CU capped at
// ~(Lmax+Lmin)/2 ~ 513 steps of work. If per-CU contention matters, this
// is ~1.5x; if pure chain latency, it's a no-op and falsifies contention.
// Eperm staging replaced by one-time scalar LDS reads -> named f4 regs
// (E-residency pattern proven R14-18); LDS ~19.5KB.
// Math (verified absmax 0.0 rounds 10/12-18):
//   fwd: a' = (E^T a) * w ; bwd: a' = E (w a); exponent-only rescale
//   every 4 steps; out = ln2 * (off_f + off_b + log2(sum_i a_i b_i)).

typedef float f2 __attribute__((ext_vector_type(2)));
typedef float f4 __attribute__((ext_vector_type(4)));

constexpr int Tt = 1024;
constexpr int Nn = 64;
constexpr int ES = 68;   // Erow stride (floats)
constexpr float LN2 = 0.69314718055994530942f;

// Pair-sum across the 32-lane halves (bit 5), order-robust: swap with a
// copy, add both outputs. s_nop 1 guards the VALU-write -> cross-lane-read
// hazard.
__device__ __forceinline__ float xsum32(float x) {
    float a = x, b = x;
    asm("s_nop 1\n\tv_permlane32_swap_b32 %0, %1" : "+v"(a), "+v"(b));
    return a + b;
}

// Kernel 1: rank chains by (length, idx); perm[rank] = idx.
__global__ __launch_bounds__(512) void rank_pairs(
    const int* __restrict__ lengths, int* __restrict__ perm, int Bb)
{
    for (int i = threadIdx.x; i < Bb; i += 512) {
        int Li = lengths[i];
        int rank = 0;
        for (int j = 0; j < Bb; ++j) {
            int Lj = lengths[j];
            rank += (Lj < Li) || (Lj == Li && j < i);
        }
        perm[rank] = i;
    }
}

__global__ __launch_bounds__(256, 1) void crf_fwd(
    const float* __restrict__ unary,
    const int*   __restrict__ lengths,
    const float* __restrict__ trans,
    const int*   __restrict__ perm,
    float*       __restrict__ out,
    int Bb)
{
    const int tid  = threadIdx.x;
    const int w4   = tid >> 6;   // wave 0..3
    const int dirW = w4 & 1;     // 0 = forward, 1 = backward
    const int c    = w4 >> 1;    // chain slot 0 (long) / 1 (short)
    const int lane = tid & 63;
    const int q    = lane & 31;  // output index low bits
    const int h    = lane >> 5;  // input half

    __shared__ float Erow[Nn * ES];              // exp(trans[i][j])
    __shared__ __align__(16) float shp[4][Nn];   // per-wave alpha broadcast
    __shared__ float shb[2][Nn];                 // beta at midpoint
    __shared__ int   sh_off_b[2];                // bwd exponent offsets

    // Stage E = exp(trans) (one-time, 256 threads).
    #pragma unroll
    for (int ci = 0; ci < (Nn * Nn) / 256; ++ci) {
        int idx = ci * 256 + tid;
        Erow[(idx >> 6) * ES + (idx & 63)] = __expf(trans[idx]);
    }
    __syncthreads();

    // Chain assignment: block i pairs sorted[i] with sorted[Bb-1-i].
    const int chain = perm[(c == 0) ? blockIdx.x : (Bb - 1 - blockIdx.x)];

    // One-time E fragment: 64 scalar LDS reads (divergent, one-time) into
    // NAMED f4 registers in R17's half-slice order, then pin.
    //   v<32:  o = q,     i = 32h + v
    //   v>=32: o = q+32,  i = 32h + (v-32)
    //   fwd: M[o][i] = E[i][o] (a' = E^T a); bwd: M[o][i] = E[o][i].
    auto EL = [&](int v) -> float {
        int o = q + 32 * (v >> 5);
        int i = 32 * h + (v & 31);
        return (dirW == 0) ? Erow[i * ES + o] : Erow[o * ES + i];
    };
    f4 EA0  = {EL(0),  EL(1),  EL(2),  EL(3)};
    f4 EA1  = {EL(4),  EL(5),  EL(6),  EL(7)};
    f4 EA2  = {EL(8),  EL(9),  EL(10), EL(11)};
    f4 EA3  = {EL(12), EL(13), EL(14), EL(15)};
    f4 EA4  = {EL(16), EL(17), EL(18), EL(19)};
    f4 EA5  = {EL(20), EL(21), EL(22), EL(23)};
    f4 EA6  = {EL(24), EL(25), EL(26), EL(27)};
    f4 EA7  = {EL(28), EL(29), EL(30), EL(31)};
    f4 EA8  = {EL(32), EL(33), EL(34), EL(35)};
    f4 EA9  = {EL(36), EL(37), EL(38), EL(39)};
    f4 EA10 = {EL(40), EL(41), EL(42), EL(43)};
    f4 EA11 = {EL(44), EL(45), EL(46), EL(47)};
    f4 EA12 = {EL(48), EL(49), EL(50), EL(51)};
    f4 EA13 = {EL(52), EL(53), EL(54), EL(55)};
    f4 EA14 = {EL(56), EL(57), EL(58), EL(59)};
    f4 EA15 = {EL(60), EL(61), EL(62), EL(63)};
    asm volatile("" : "+v"(EA0),  "+v"(EA1),  "+v"(EA2),  "+v"(EA3),
                      "+v"(EA4),  "+v"(EA5),  "+v"(EA6),  "+v"(EA7),
                      "+v"(EA8),  "+v"(EA9),  "+v"(EA10), "+v"(EA11),
                      "+v"(EA12), "+v"(EA13), "+v"(EA14), "+v"(EA15));

    int L = lengths[chain];
    L = L < 1 ? 1 : (L > Tt ? Tt : L);
    const int m2 = (L - 1) >> 1;

    const float* ub = unary + (size_t)chain * Tt * Nn;

    const int trips = (dirW == 0) ? m2 : (L - 1 - m2);
    const int tbase = (dirW == 0) ? 1 : (L - 1);
    const int dir   = (dirW == 0) ? 1 : -1;

    // Exp-domain state + exponent offset.
    float acc = (dirW == 0) ? __expf(ub[lane]) : 1.0f;
    int   off = 0;

    float* myp = shp[w4];
    const f4* rowp = (const f4*)&shp[w4][32 * h];  // half-uniform address

    // 8-step lookahead: wq* = exp'd w for steps s0..s0+3,
    //                   uq* = raw u for steps s0+4..s0+7.
    const int smax = trips > 0 ? trips - 1 : 0;
    float wq0, wq1, wq2, wq3, uq0, uq1, uq2, uq3;
    {
        int c0 = 0 < smax ? 0 : smax, c1 = 1 < smax ? 1 : smax;
        int c2 = 2 < smax ? 2 : smax, c3 = 3 < smax ? 3 : smax;
        wq0 = __expf(ub[(tbase + dir * c0) * Nn + lane]);
        wq1 = __expf(ub[(tbase + dir * c1) * Nn + lane]);
        wq2 = __expf(ub[(tbase + dir * c2) * Nn + lane]);
        wq3 = __expf(ub[(tbase + dir * c3) * Nn + lane]);
        int c4 = 4 < smax ? 4 : smax, c5 = 5 < smax ? 5 : smax;
        int c6 = 6 < smax ? 6 : smax, c7 = 7 < smax ? 7 : smax;
        uq0 = ub[(tbase + dir * c4) * Nn + lane];
        uq1 = ub[(tbase + dir * c5) * Nn + lane];
        uq2 = ub[(tbase + dir * c6) * Nn + lane];
        uq3 = ub[(tbase + dir * c7) * Nn + lane];
    }

    for (int s0 = 0; s0 < trips; s0 += 4) {
        // Issue raw loads 8 ahead; exp the 4-ahead batch. Both off-chain.
        float un0, un1, un2, un3, wn0, wn1, wn2, wn3;
        {
            int c0 = s0 + 8,  c1 = s0 + 9,  c2 = s0 + 10, c3 = s0 + 11;
            c0 = c0 > smax ? smax : c0;  c1 = c1 > smax ? smax : c1;
            c2 = c2 > smax ? smax : c2;  c3 = c3 > smax ? smax : c3;
            un0 = ub[(tbase + dir * c0) * Nn + lane];
            un1 = ub[(tbase + dir * c1) * Nn + lane];
            un2 = ub[(tbase + dir * c2) * Nn + lane];
            un3 = ub[(tbase + dir * c3) * Nn + lane];
        }
        wn0 = __expf(uq0); wn1 = __expf(uq1);
        wn2 = __expf(uq2); wn3 = __expf(uq3);

        #pragma unroll
        for (int k = 0; k < 4; ++k) {
            if (s0 + k >= trips) break;  // wave-uniform

            float wk = (k == 0) ? wq0 : (k == 1) ? wq1 : (k == 2) ? wq2 : wq3;

            // fwd: a' = (E^T a) * w   (w on output)
            // bwd: a' = E (w * a)     (w on input)
            float src = (dirW != 0) ? acc * wk : acc;

            // Publish alpha; read own input half (8x b128, half-uniform
            // address -> broadcast). Same-wave DS ops are in-order.
            myp[lane] = src;
            f4 av0 = rowp[0], av1 = rowp[1], av2 = rowp[2], av3 = rowp[3];
            f4 av4 = rowp[4], av5 = rowp[5], av6 = rowp[6], av7 = rowp[7];

            // Partials: Pa = <half, M[q][half]>, Pb = <half, M[q+32][half]>.
            f4 Aa = av0 * EA0;       f4 Ab = av1 * EA1;
            Aa = av2 * EA2 + Aa;     Ab = av3 * EA3 + Ab;
            Aa = av4 * EA4 + Aa;     Ab = av5 * EA5 + Ab;
            Aa = av6 * EA6 + Aa;     Ab = av7 * EA7 + Ab;
            f4 Ba = av0 * EA8;       f4 Bb = av1 * EA9;
            Ba = av2 * EA10 + Ba;    Bb = av3 * EA11 + Bb;
            Ba = av4 * EA12 + Ba;    Bb = av5 * EA13 + Bb;
            Ba = av6 * EA14 + Ba;    Bb = av7 * EA15 + Bb;

            f4 At = Aa + Ab;         f4 Bt = Ba + Bb;
            f2 Ah = At.xy + At.zw;   f2 Bh = Bt.xy + Bt.zw;
            float Pa = Ah[0] + Ah[1];
            float Pb = Bh[0] + Bh[1];

            // Cross-half reduce: one permlane32 pair-sum per output.
            float za = xsum32(Pa);   // out[q],    replicated both halves
            float zb = xsum32(Pb);   // out[q+32], replicated both halves
            float z  = (lane & 32) ? zb : za;

            acc = (dirW == 0) ? z * wk : z;
        }

        // Exact exponent-only rescale (once per 4 steps; keeps fp32 in
        // range: worst drift 4 steps * ~14 bits + ~10 bits lane spread).
        {
            unsigned s0b = (unsigned)__builtin_amdgcn_readfirstlane(
                (int)__float_as_uint(acc));
            int e = (int)((s0b >> 23) & 0xFF) - 127;
            off += e;
            acc *= __uint_as_float((unsigned)(127 - e) << 23);
        }

        wq0 = wn0; wq1 = wn1; wq2 = wn2; wq3 = wn3;
        uq0 = un0; uq1 = un1; uq2 = un2; uq3 = un3;
    }

    // Combine per chain: out = ln2*(off_f + off_b + log2(sum_i a_i b_i)).
    if (dirW == 1) {
        shb[c][lane] = acc;
        if (lane == 0) sh_off_b[c] = off;
    }
    __syncthreads();
    if (dirW == 0) {
        float v = acc * shb[c][lane];
        float ssum = v;
        #pragma unroll
        for (int k = 32; k >= 1; k >>= 1)
            ssum += __shfl_xor(ssum, k, 64);
        if (lane == 0) {
            float l2 = __builtin_amdgcn_logf(ssum);  // v_log_f32 = log2
            out[chain] = LN2 * ((float)(off + sh_off_b[c]) + l2);
        }
    }
}

extern "C" void kernel_launch(void* const* d_in, const int* in_sizes, int n_in,
                              void* d_out, int out_size, void* d_ws, size_t ws_size,
                              hipStream_t stream) {
    const float* unary   = (const float*)d_in[0];
    const int*   lengths = (const int*)d_in[1];
    const float* trans   = (const float*)d_in[2];
    float*       out     = (float*)d_out;
    int*         perm    = (int*)d_ws;

    const int Bb = in_sizes[1];  // 512
    rank_pairs<<<1, 512, 0, stream>>>(lengths, perm, Bb);
    crf_fwd<<<(Bb + 1) / 2, 256, 0, stream>>>(unary, lengths, trans, perm,
                                              out, Bb);
}